// Round 4
// baseline (141.705 us; speedup 1.0000x reference)
//
#include <hip/hip_runtime.h>
#include <stdint.h>

#define DDIM 1024
#define HH 16
#define HDIM 64
#define SS 2048

typedef short bf16x8 __attribute__((ext_vector_type(8)));
typedef short bf16x4 __attribute__((ext_vector_type(4)));
typedef float f32x4 __attribute__((ext_vector_type(4)));
typedef unsigned short u16;

__device__ __forceinline__ unsigned f2bf(float f) {
  unsigned u = __builtin_bit_cast(unsigned, f);
  u = u + 0x7FFFu + ((u >> 16) & 1u);   // RNE (inputs finite)
  return u >> 16;
}

// packs RNE-converted a->lo16, b->hi16
__device__ __forceinline__ unsigned cvt_pk_bf16(float a, float b) {
  unsigned r;
  asm("v_cvt_pk_bf16_f32 %0, %1, %2" : "=v"(r) : "v"(a), "v"(b));
  return r;
}

__device__ __forceinline__ void mfma16(f32x4& c, bf16x4 a, bf16x4 b) {
  asm("v_mfma_f32_16x16x16_bf16 %0, %1, %2, %0" : "+v"(c) : "v"(a), "v"(b));
}

__device__ __forceinline__ void gload16(const void* g, void* l) {
  __builtin_amdgcn_global_load_lds(
      (const __attribute__((address_space(1))) unsigned int*)g,
      (__attribute__((address_space(3))) unsigned int*)l, 16, 0, 0);
}

// ---------------- convert x: fp32 -> bf16 ----------------
__global__ void k_convert_x(const float* __restrict__ x, u16* __restrict__ xb) {
  int i = (blockIdx.x * 256 + threadIdx.x) * 4;
  float4 v = *(const float4*)(x + i);
  ushort4 o;
  o.x = (u16)f2bf(v.x); o.y = (u16)f2bf(v.y); o.z = (u16)f2bf(v.z); o.w = (u16)f2bf(v.w);
  *(ushort4*)(xb + i) = o;
}

// ---------------- transpose+convert weights: W[k][n] -> WT[n][k] bf16 ----------------
__global__ void k_transpose_w(const float* __restrict__ w0, const float* __restrict__ w1,
                              const float* __restrict__ w2, const float* __restrict__ w3,
                              u16* __restrict__ wt) {
  __shared__ float t[64][65];
  int z = blockIdx.z;
  const float* src = (z == 0) ? w0 : (z == 1) ? w1 : (z == 2) ? w2 : w3;
  u16* dst = wt + (size_t)z * DDIM * DDIM;
  int k0 = blockIdx.x * 64, n0 = blockIdx.y * 64;
  int tid = threadIdx.x;
  int c4 = tid & 15, rr = tid >> 4;
  for (int rep = 0; rep < 4; rep++) {
    int r = rr + rep * 16;
    float4 v = *(const float4*)(src + (size_t)(k0 + r) * DDIM + n0 + c4 * 4);
    t[r][c4 * 4 + 0] = v.x; t[r][c4 * 4 + 1] = v.y;
    t[r][c4 * 4 + 2] = v.z; t[r][c4 * 4 + 3] = v.w;
  }
  __syncthreads();
  for (int rep = 0; rep < 4; rep++) {
    int n = rr + rep * 16;
    ushort4 o;
    o.x = (u16)f2bf(t[c4 * 4 + 0][n]); o.y = (u16)f2bf(t[c4 * 4 + 1][n]);
    o.z = (u16)f2bf(t[c4 * 4 + 2][n]); o.w = (u16)f2bf(t[c4 * 4 + 3][n]);
    *(ushort4*)(dst + (size_t)(n0 + n) * DDIM + k0 + c4 * 4) = o;
  }
}

// ---------------- GEMM: tile 128x128, BK=64, K=1024; A[m][k], BT[n][k] bf16 ----------------
// MODE 0: fused QKV (which=blockIdx.y>>3: 0->Qb (+bias, *0.125*log2e), 1->Kb, 2->Vt transposed)
// MODE 1: fp32 out + bias (final projection)
template <int MODE>
__global__ __launch_bounds__(256, 2) void k_gemm(const u16* __restrict__ A,
                                                 const u16* __restrict__ BT,
                                                 const float* __restrict__ bias,
                                                 void* __restrict__ O0,
                                                 void* __restrict__ O1,
                                                 void* __restrict__ O2) {
  __shared__ __align__(16) u16 lA[128 * 64];
  __shared__ __align__(16) u16 lB[128 * 64];
  const int tid = threadIdx.x;
  const int l = tid & 63, w = tid >> 6;
  const int wm = w >> 1, wn = w & 1;
  const int m0 = blockIdx.x * 128, n0 = blockIdx.y * 128;
  const int lr = l >> 4, lc = l & 15;

  const int srow = l >> 3;
  const int scol = ((l & 7) ^ srow) * 8;

  f32x4 acc[4][4];
  for (int mi = 0; mi < 4; mi++)
    for (int ni = 0; ni < 4; ni++)
      acc[mi][ni] = f32x4{0.f, 0.f, 0.f, 0.f};

  for (int kk = 0; kk < 16; kk++) {
    const int k0 = kk * 64;
    for (int i = 0; i < 4; i++) {
      int c = w * 4 + i;
      gload16(A + (size_t)(m0 + c * 8 + srow) * DDIM + k0 + scol, (char*)lA + c * 1024);
      gload16(BT + (size_t)(n0 + c * 8 + srow) * DDIM + k0 + scol, (char*)lB + c * 1024);
    }
    __syncthreads();
    for (int ks = 0; ks < 2; ks++) {
      bf16x8 af[4], bfr[4];
      for (int mi = 0; mi < 4; mi++) {
        int row = wm * 64 + mi * 16 + lc;
        int slot = (ks * 4 + lr) ^ (row & 7);
        af[mi] = *(const bf16x8*)((const char*)lA + row * 128 + slot * 16);
      }
      for (int ni = 0; ni < 4; ni++) {
        int row = wn * 64 + ni * 16 + lc;
        int slot = (ks * 4 + lr) ^ (row & 7);
        bfr[ni] = *(const bf16x8*)((const char*)lB + row * 128 + slot * 16);
      }
      for (int mi = 0; mi < 4; mi++)
        for (int ni = 0; ni < 4; ni++)
          acc[mi][ni] = __builtin_amdgcn_mfma_f32_16x16x32_bf16(af[mi], bfr[ni], acc[mi][ni], 0, 0, 0);
    }
    __syncthreads();
  }

  if (MODE == 0) {
    const int which = blockIdx.y >> 3;   // uniform per block
    if (which == 0) {
      u16* C = (u16*)O0;
      const float c1 = 0.18033688011112043f;  // 0.125 * log2(e) folded into Q
      for (int mi = 0; mi < 4; mi++)
        for (int ni = 0; ni < 4; ni++) {
          int nl = (n0 + wn * 64 + ni * 16 + lc) & 1023;
          float badd = bias[nl];
          for (int r = 0; r < 4; r++) {
            int m = m0 + wm * 64 + mi * 16 + lr * 4 + r;
            C[(size_t)m * DDIM + nl] = (u16)f2bf((acc[mi][ni][r] + badd) * c1);
          }
        }
    } else if (which == 1) {
      u16* C = (u16*)O1;
      for (int mi = 0; mi < 4; mi++)
        for (int ni = 0; ni < 4; ni++) {
          int nl = (n0 + wn * 64 + ni * 16 + lc) & 1023;
          for (int r = 0; r < 4; r++) {
            int m = m0 + wm * 64 + mi * 16 + lr * 4 + r;
            C[(size_t)m * DDIM + nl] = (u16)f2bf(acc[mi][ni][r]);
          }
        }
    } else {
      u16* C = (u16*)O2;  // [bh][hd][s]
      for (int mi = 0; mi < 4; mi++)
        for (int ni = 0; ni < 4; ni++) {
          int nl = (n0 + wn * 64 + ni * 16 + lc) & 1023;
          int h = nl >> 6, hd = nl & 63;
          int m = m0 + wm * 64 + mi * 16 + lr * 4;
          int b = m >> 11, s = m & 2047;
          unsigned d0 = f2bf(acc[mi][ni][0]) | (f2bf(acc[mi][ni][1]) << 16);
          unsigned d1 = f2bf(acc[mi][ni][2]) | (f2bf(acc[mi][ni][3]) << 16);
          u16* p = C + ((size_t)((b * HH + h) * HDIM + hd)) * SS + s;
          *(unsigned*)(p) = d0;
          *(unsigned*)(p + 2) = d1;
        }
    }
  } else {
    float* C = (float*)O0;
    for (int mi = 0; mi < 4; mi++)
      for (int ni = 0; ni < 4; ni++) {
        int n = n0 + wn * 64 + ni * 16 + lc;
        float badd = bias[n];
        for (int r = 0; r < 4; r++) {
          int m = m0 + wm * 64 + mi * 16 + lr * 4 + r;
          C[(size_t)m * DDIM + n] = acc[mi][ni][r] + badd;
        }
      }
  }
}

// ---------------- flash attention tile body ----------------
// exp2-domain: Q pre-scaled by 0.125*log2e; sv = S2 - slope2*key; p = exp2(sv - m)
// denominator: sum of UNROUNDED p (R1 numerics, absmax 0.0078); P rounded only for PV
__device__ __forceinline__ void attn_tile(int kt, bool masked, int kfhi,
                                          const char* lKc, const char* lVc,
                                          const bf16x8 qf[2], f32x4 of[4],
                                          float& mrun, float& lrun,
                                          float slope2, int lr, int lc, int q_glob) {
  // S^T[key][q] = K . Q^T
  f32x4 sf[8];
#pragma unroll
  for (int kf = 0; kf < 8; kf++) sf[kf] = f32x4{0.f, 0.f, 0.f, 0.f};
  __builtin_amdgcn_s_setprio(1);
#pragma unroll
  for (int ks = 0; ks < 2; ks++)
#pragma unroll
    for (int kf = 0; kf < 8; kf++) {
      if (kf >= kfhi) continue;
      int key = kf * 16 + lc;
      int slot = (ks * 4 + lr) ^ (lc & 7);
      bf16x8 a = *(const bf16x8*)(lKc + key * 128 + slot * 16);
      sf[kf] = __builtin_amdgcn_mfma_f32_16x16x32_bf16(a, qf[ks], sf[kf], 0, 0, 0);
    }
  __builtin_amdgcn_s_setprio(0);

  // ALiBi (exp2 domain) + causal mask + column max
  const float kbase = -slope2 * (float)(kt * 128 + lr * 4);
  float tmax = -3.0e38f;
#pragma unroll
  for (int kf = 0; kf < 8; kf++) {
    if (kf >= kfhi) continue;
#pragma unroll
    for (int r = 0; r < 4; r++) {
      float sv = sf[kf][r] + (kbase - slope2 * (float)(kf * 16 + r));
      if (masked) {
        int key = kt * 128 + kf * 16 + lr * 4 + r;
        if (key > q_glob) sv = -3.0e38f;
      }
      sf[kf][r] = sv;
      tmax = fmaxf(tmax, sv);
    }
  }
  tmax = fmaxf(tmax, __shfl_xor(tmax, 16));
  tmax = fmaxf(tmax, __shfl_xor(tmax, 32));

  // conditional rescale (exact: skipping is the corr==1 case)
  if (tmax > mrun) {
    float corr = exp2f(mrun - tmax);
    lrun *= corr;
#pragma unroll
    for (int mf = 0; mf < 4; mf++) {
      of[mf][0] *= corr; of[mf][1] *= corr; of[mf][2] *= corr; of[mf][3] *= corr;
    }
    mrun = tmax;
  }

  // p = exp2(sv - m); UNROUNDED sum for denominator; cvt_pk pack for PV
  f32x4 ps = f32x4{0.f, 0.f, 0.f, 0.f};
  bf16x4 pb[8];
#pragma unroll
  for (int kf = 0; kf < 8; kf++) {
    if (kf >= kfhi) continue;
    float p0 = exp2f(sf[kf][0] - mrun);
    float p1 = exp2f(sf[kf][1] - mrun);
    float p2 = exp2f(sf[kf][2] - mrun);
    float p3 = exp2f(sf[kf][3] - mrun);
    ps[0] += p0; ps[1] += p1; ps[2] += p2; ps[3] += p3;
    uint2 uu;
    uu.x = cvt_pk_bf16(p0, p1);
    uu.y = cvt_pk_bf16(p2, p3);
    pb[kf] = __builtin_bit_cast(bf16x4, uu);
  }
  float psum = (ps[0] + ps[1]) + (ps[2] + ps[3]);
  psum += __shfl_xor(psum, 16);
  psum += __shfl_xor(psum, 32);
  lrun += psum;

  // O^T[hd][q] += V^T . P   (A = V b64 frags, B = in-register P)
  __builtin_amdgcn_s_setprio(1);
#pragma unroll
  for (int kf = 0; kf < 8; kf++) {
    if (kf >= kfhi) continue;
    int g2 = (kf << 1) + (lr >> 1);
#pragma unroll
    for (int mf = 0; mf < 4; mf++) {
      int hd = mf * 16 + lc;
      int byte = hd * 256 + ((g2 ^ (hd & 7)) << 4) + ((lr & 1) << 3);
      bf16x4 va = *(const bf16x4*)(lVc + byte);
      mfma16(of[mf], va, pb[kf]);
    }
  }
  __builtin_amdgcn_s_setprio(0);
}

__global__ __launch_bounds__(256, 4) void k_attn(const u16* __restrict__ Q,
                                                 const u16* __restrict__ Kg,
                                                 const u16* __restrict__ Vt,
                                                 u16* __restrict__ AO) {
  __shared__ __align__(16) u16 lK[128 * 64];  // [key][hd], XOR-swizzled 16B slots
  __shared__ __align__(16) u16 lV[64 * 128];  // [hd][key], XOR-swizzled 16B slots

  const int tid = threadIdx.x;
  const int l = tid & 63, w = tid >> 6;
  const int lr = l >> 4, lc = l & 15;
  // 1-D grid, work-interleaved: consecutive ids get qt pairs {k, 31-k} (17 tiles/pair),
  // bh in high bits so 32 consecutive blocks share K/V in L2.
  const int id = blockIdx.x;
  const int bh = id >> 5;
  const int p5 = id & 31;
  const int kq = p5 >> 1;
  const int qt = (p5 & 1) ? (31 - kq) : kq;
  const int b = bh >> 4, h = bh & 15;

  const float slope2 = exp2f(-0.5f * (float)(h + 1)) * 1.4426950408889634f;
  const int q_glob = qt * 64 + w * 16 + lc;

  bf16x8 qf[2];
#pragma unroll
  for (int ks = 0; ks < 2; ks++)
    qf[ks] = *(const bf16x8*)(Q + (size_t)(b * SS + q_glob) * DDIM + h * HDIM + ks * 32 + lr * 8);

  f32x4 of[4];
#pragma unroll
  for (int mf = 0; mf < 4; mf++) of[mf] = f32x4{0.f, 0.f, 0.f, 0.f};
  float mrun = -3.0e38f, lrun = 0.f;

  const int srowK = l >> 3;
  const int scolK = ((l & 7) ^ srowK) * 8;
  const int nkt = qt / 2 + 1;

  auto stage = [&](int kt) {
#pragma unroll
    for (int i = 0; i < 4; i++) {
      int c = w * 4 + i;
      gload16(Kg + (size_t)(b * SS + kt * 128 + c * 8 + srowK) * DDIM + h * HDIM + scolK,
              (char*)lK + c * 1024);
      int hd = c * 4 + lr;
      gload16(Vt + ((size_t)bh * HDIM + hd) * SS + kt * 128 + (((l & 15) ^ (hd & 7)) << 3),
              (char*)lV + c * 1024);
    }
  };

  for (int kt = 0; kt < nkt - 1; kt++) {
    stage(kt);
    __syncthreads();
    attn_tile(kt, false, 8, (const char*)lK, (const char*)lV, qf, of, mrun, lrun,
              slope2, lr, lc, q_glob);
    __syncthreads();
  }
  stage(nkt - 1);
  __syncthreads();
  if (qt & 1)
    attn_tile(nkt - 1, true, 8, (const char*)lK, (const char*)lV, qf, of, mrun, lrun,
              slope2, lr, lc, q_glob);
  else
    attn_tile(nkt - 1, true, 4, (const char*)lK, (const char*)lV, qf, of, mrun, lrun,
              slope2, lr, lc, q_glob);

  float inv = 1.f / lrun;
  u16* obase = AO + (size_t)(b * SS + q_glob) * DDIM + h * HDIM;
#pragma unroll
  for (int mf = 0; mf < 4; mf++) {
    uint2 uu;
    uu.x = cvt_pk_bf16(of[mf][0] * inv, of[mf][1] * inv);
    uu.y = cvt_pk_bf16(of[mf][2] * inv, of[mf][3] * inv);
    *(uint2*)(obase + mf * 16 + lr * 4) = uu;
  }
}

extern "C" void kernel_launch(void* const* d_in, const int* in_sizes, int n_in,
                              void* d_out, int out_size, void* d_ws, size_t ws_size,
                              hipStream_t stream) {
  const float* x  = (const float*)d_in[0];
  const float* Wq = (const float*)d_in[1];
  const float* bq = (const float*)d_in[2];
  const float* Wk = (const float*)d_in[3];
  const float* Wv = (const float*)d_in[4];
  const float* Wo = (const float*)d_in[5];
  const float* bo = (const float*)d_in[6];
  float* out = (float*)d_out;

  u16* ws = (u16*)d_ws;
  const size_t MEG = 1024 * 1024;
  u16* xb = ws;                  // 4M elems
  u16* WT = ws + 4 * MEG;        // 4 x 1M elems: WqT,WkT,WvT,WoT
  u16* Qb = ws + 8 * MEG;        // 4M
  u16* Kb = ws + 12 * MEG;       // 4M
  u16* Vt = ws + 16 * MEG;       // 4M  [32][64][2048]
  u16* AO = ws + 20 * MEG;       // 4M

  k_convert_x<<<dim3(4096), dim3(256), 0, stream>>>(x, xb);
  k_transpose_w<<<dim3(16, 16, 4), dim3(256), 0, stream>>>(Wq, Wk, Wv, Wo, WT);
  k_gemm<0><<<dim3(32, 24), dim3(256), 0, stream>>>(xb, WT, bq, (void*)Qb, (void*)Kb, (void*)Vt);
  k_attn<<<dim3(1024), dim3(256), 0, stream>>>(Qb, Kb, Vt, AO);
  k_gemm<1><<<dim3(32, 8), dim3(256), 0, stream>>>(AO, WT + 3 * MEG, bo, (void*)out, nullptr, nullptr);
}

// Round 5
// 121.151 us; speedup vs baseline: 1.1697x; 1.1697x over previous
//
#include <hip/hip_runtime.h>
#include <stdint.h>

#define DDIM 1024
#define HH 16
#define HDIM 64
#define SS 2048

typedef short bf16x8 __attribute__((ext_vector_type(8)));
typedef float f32x4 __attribute__((ext_vector_type(4)));
typedef unsigned short u16;

__device__ __forceinline__ unsigned f2bf(float f) {
  unsigned u = __builtin_bit_cast(unsigned, f);
  u = u + 0x7FFFu + ((u >> 16) & 1u);   // RNE (inputs finite)
  return u >> 16;
}

__device__ __forceinline__ void gload16(const void* g, void* l) {
  __builtin_amdgcn_global_load_lds(
      (const __attribute__((address_space(1))) unsigned int*)g,
      (__attribute__((address_space(3))) unsigned int*)l, 16, 0, 0);
}

// ---------------- convert x: fp32 -> bf16 ----------------
__global__ void k_convert_x(const float* __restrict__ x, u16* __restrict__ xb) {
  int i = (blockIdx.x * 256 + threadIdx.x) * 4;
  float4 v = *(const float4*)(x + i);
  ushort4 o;
  o.x = (u16)f2bf(v.x); o.y = (u16)f2bf(v.y); o.z = (u16)f2bf(v.z); o.w = (u16)f2bf(v.w);
  *(ushort4*)(xb + i) = o;
}

// ---------------- transpose+convert weights: W[k][n] -> WT[n][k] bf16 ----------------
__global__ void k_transpose_w(const float* __restrict__ w0, const float* __restrict__ w1,
                              const float* __restrict__ w2, const float* __restrict__ w3,
                              u16* __restrict__ wt) {
  __shared__ float t[64][65];
  int z = blockIdx.z;
  const float* src = (z == 0) ? w0 : (z == 1) ? w1 : (z == 2) ? w2 : w3;
  u16* dst = wt + (size_t)z * DDIM * DDIM;
  int k0 = blockIdx.x * 64, n0 = blockIdx.y * 64;
  int tid = threadIdx.x;
  int c4 = tid & 15, rr = tid >> 4;
  for (int rep = 0; rep < 4; rep++) {
    int r = rr + rep * 16;
    float4 v = *(const float4*)(src + (size_t)(k0 + r) * DDIM + n0 + c4 * 4);
    t[r][c4 * 4 + 0] = v.x; t[r][c4 * 4 + 1] = v.y;
    t[r][c4 * 4 + 2] = v.z; t[r][c4 * 4 + 3] = v.w;
  }
  __syncthreads();
  for (int rep = 0; rep < 4; rep++) {
    int n = rr + rep * 16;
    ushort4 o;
    o.x = (u16)f2bf(t[c4 * 4 + 0][n]); o.y = (u16)f2bf(t[c4 * 4 + 1][n]);
    o.z = (u16)f2bf(t[c4 * 4 + 2][n]); o.w = (u16)f2bf(t[c4 * 4 + 3][n]);
    *(ushort4*)(dst + (size_t)(n0 + n) * DDIM + k0 + c4 * 4) = o;
  }
}

// ---------------- GEMM: tile 128x128, BK=64, K=1024; A[m][k], BT[n][k] bf16 ----------------
// MODE 0: fused QKV (which=blockIdx.y>>3: 0->Qb (+bias), 1->Kb, 2->Vt transposed)
// MODE 1: fp32 out + bias (final projection)
template <int MODE>
__global__ __launch_bounds__(256, 2) void k_gemm(const u16* __restrict__ A,
                                                 const u16* __restrict__ BT,
                                                 const float* __restrict__ bias,
                                                 void* __restrict__ O0,
                                                 void* __restrict__ O1,
                                                 void* __restrict__ O2) {
  __shared__ __align__(16) u16 lA[128 * 64];
  __shared__ __align__(16) u16 lB[128 * 64];
  const int tid = threadIdx.x;
  const int l = tid & 63, w = tid >> 6;
  const int wm = w >> 1, wn = w & 1;
  const int m0 = blockIdx.x * 128, n0 = blockIdx.y * 128;
  const int lr = l >> 4, lc = l & 15;

  const int srow = l >> 3;
  const int scol = ((l & 7) ^ srow) * 8;

  f32x4 acc[4][4];
  for (int mi = 0; mi < 4; mi++)
    for (int ni = 0; ni < 4; ni++)
      acc[mi][ni] = f32x4{0.f, 0.f, 0.f, 0.f};

  for (int kk = 0; kk < 16; kk++) {
    const int k0 = kk * 64;
    for (int i = 0; i < 4; i++) {
      int c = w * 4 + i;
      gload16(A + (size_t)(m0 + c * 8 + srow) * DDIM + k0 + scol, (char*)lA + c * 1024);
      gload16(BT + (size_t)(n0 + c * 8 + srow) * DDIM + k0 + scol, (char*)lB + c * 1024);
    }
    __syncthreads();
    for (int ks = 0; ks < 2; ks++) {
      bf16x8 af[4], bfr[4];
      for (int mi = 0; mi < 4; mi++) {
        int row = wm * 64 + mi * 16 + lc;
        int slot = (ks * 4 + lr) ^ (row & 7);
        af[mi] = *(const bf16x8*)((const char*)lA + row * 128 + slot * 16);
      }
      for (int ni = 0; ni < 4; ni++) {
        int row = wn * 64 + ni * 16 + lc;
        int slot = (ks * 4 + lr) ^ (row & 7);
        bfr[ni] = *(const bf16x8*)((const char*)lB + row * 128 + slot * 16);
      }
      for (int mi = 0; mi < 4; mi++)
        for (int ni = 0; ni < 4; ni++)
          acc[mi][ni] = __builtin_amdgcn_mfma_f32_16x16x32_bf16(af[mi], bfr[ni], acc[mi][ni], 0, 0, 0);
    }
    __syncthreads();
  }

  if (MODE == 0) {
    const int which = blockIdx.y >> 3;   // uniform per block
    if (which == 0) {
      u16* C = (u16*)O0;
      for (int mi = 0; mi < 4; mi++)
        for (int ni = 0; ni < 4; ni++) {
          int nl = (n0 + wn * 64 + ni * 16 + lc) & 1023;
          float badd = bias[nl];
          for (int r = 0; r < 4; r++) {
            int m = m0 + wm * 64 + mi * 16 + lr * 4 + r;
            C[(size_t)m * DDIM + nl] = (u16)f2bf(acc[mi][ni][r] + badd);
          }
        }
    } else if (which == 1) {
      u16* C = (u16*)O1;
      for (int mi = 0; mi < 4; mi++)
        for (int ni = 0; ni < 4; ni++) {
          int nl = (n0 + wn * 64 + ni * 16 + lc) & 1023;
          for (int r = 0; r < 4; r++) {
            int m = m0 + wm * 64 + mi * 16 + lr * 4 + r;
            C[(size_t)m * DDIM + nl] = (u16)f2bf(acc[mi][ni][r]);
          }
        }
    } else {
      u16* C = (u16*)O2;  // [bh][hd][s]
      for (int mi = 0; mi < 4; mi++)
        for (int ni = 0; ni < 4; ni++) {
          int nl = (n0 + wn * 64 + ni * 16 + lc) & 1023;
          int h = nl >> 6, hd = nl & 63;
          int m = m0 + wm * 64 + mi * 16 + lr * 4;
          int b = m >> 11, s = m & 2047;
          unsigned d0 = f2bf(acc[mi][ni][0]) | (f2bf(acc[mi][ni][1]) << 16);
          unsigned d1 = f2bf(acc[mi][ni][2]) | (f2bf(acc[mi][ni][3]) << 16);
          u16* p = C + ((size_t)((b * HH + h) * HDIM + hd)) * SS + s;
          *(unsigned*)(p) = d0;
          *(unsigned*)(p + 2) = d1;
        }
    }
  } else {
    float* C = (float*)O0;
    for (int mi = 0; mi < 4; mi++)
      for (int ni = 0; ni < 4; ni++) {
        int n = n0 + wn * 64 + ni * 16 + lc;
        float badd = bias[n];
        for (int r = 0; r < 4; r++) {
          int m = m0 + wm * 64 + mi * 16 + lr * 4 + r;
          C[(size_t)m * DDIM + n] = acc[mi][ni][r] + badd;
        }
      }
  }
}

// ---------------- flash attention tile body (R1-exact numerics) ----------------
// sv = S*0.125 - slope*key; p = __expf(sv-m); LDS-bounced bf16 P; PV via mfma_16x16x32
__device__ __forceinline__ void attn_tile(int kt, bool masked, int kfhi,
                                          const char* lKc, const char* lVc, char* lPw,
                                          const bf16x8 qf[2], f32x4 of[4],
                                          float& mrun, float& lrun,
                                          float slope, int lr, int lc, int q_glob) {
  // S^T[key][q] = K . Q^T
  f32x4 sf[8];
#pragma unroll
  for (int kf = 0; kf < 8; kf++) sf[kf] = f32x4{0.f, 0.f, 0.f, 0.f};
  __builtin_amdgcn_s_setprio(1);
#pragma unroll
  for (int ks = 0; ks < 2; ks++)
#pragma unroll
    for (int kf = 0; kf < 8; kf++) {
      if (kf >= kfhi) continue;
      int key = kf * 16 + lc;
      int slot = (ks * 4 + lr) ^ (lc & 7);
      bf16x8 a = *(const bf16x8*)(lKc + key * 128 + slot * 16);
      sf[kf] = __builtin_amdgcn_mfma_f32_16x16x32_bf16(a, qf[ks], sf[kf], 0, 0, 0);
    }
  __builtin_amdgcn_s_setprio(0);

  // scale + ALiBi + causal mask + column max (R1 formulas)
  float tmax = -INFINITY;
#pragma unroll
  for (int kf = 0; kf < 8; kf++) {
    if (kf >= kfhi) continue;
#pragma unroll
    for (int r = 0; r < 4; r++) {
      int key = kt * 128 + kf * 16 + lr * 4 + r;
      float sv = sf[kf][r] * 0.125f - slope * (float)key;
      if (masked && key > q_glob) sv = -1e9f;
      sf[kf][r] = sv;
      tmax = fmaxf(tmax, sv);
    }
  }
  tmax = fmaxf(tmax, __shfl_xor(tmax, 16));
  tmax = fmaxf(tmax, __shfl_xor(tmax, 32));

  // conditional rescale (exact: skip is the corr==1 case)
  if (tmax > mrun) {
    float corr = __expf(mrun - tmax);
    lrun *= corr;
#pragma unroll
    for (int mf = 0; mf < 4; mf++) {
      of[mf][0] *= corr; of[mf][1] *= corr; of[mf][2] *= corr; of[mf][3] *= corr;
    }
    mrun = tmax;
  }

  // p = exp(sv-m): unrounded psum; bf16 P -> per-wave LDS (packed u32 writes)
  f32x4 ps = f32x4{0.f, 0.f, 0.f, 0.f};
#pragma unroll
  for (int kf = 0; kf < 8; kf++) {
    if (kf >= kfhi) continue;
    float p0 = __expf(sf[kf][0] - mrun);
    float p1 = __expf(sf[kf][1] - mrun);
    float p2 = __expf(sf[kf][2] - mrun);
    float p3 = __expf(sf[kf][3] - mrun);
    ps[0] += p0; ps[1] += p1; ps[2] += p2; ps[3] += p3;
    int g2 = (kf << 1) + (lr >> 1);
    char* base = lPw + lc * 256 + ((g2 ^ (lc & 7)) << 4) + ((lr & 1) << 3);
    *(unsigned*)(base) = f2bf(p0) | (f2bf(p1) << 16);
    *(unsigned*)(base + 4) = f2bf(p2) | (f2bf(p3) << 16);
  }
  float psum = (ps[0] + ps[1]) + (ps[2] + ps[3]);
  psum += __shfl_xor(psum, 16);
  psum += __shfl_xor(psum, 32);
  lrun += psum;

  // O^T[hd][q] += V^T . P  (mfma_16x16x32, b128 reads of V and P)
  const int kshi = kfhi >> 1;
  __builtin_amdgcn_s_setprio(1);
#pragma unroll
  for (int ks = 0; ks < 4; ks++) {
    if (ks >= kshi) continue;
    int slotp = (ks * 4 + lr) ^ (lc & 7);
    bf16x8 pb = *(const bf16x8*)(lPw + lc * 256 + slotp * 16);
#pragma unroll
    for (int mf = 0; mf < 4; mf++) {
      int hd = mf * 16 + lc;
      int slotv = (ks * 4 + lr) ^ (hd & 7);
      bf16x8 va = *(const bf16x8*)(lVc + hd * 256 + slotv * 16);
      of[mf] = __builtin_amdgcn_mfma_f32_16x16x32_bf16(va, pb, of[mf], 0, 0, 0);
    }
  }
  __builtin_amdgcn_s_setprio(0);
}

__global__ __launch_bounds__(256, 2) void k_attn(const u16* __restrict__ Q,
                                                 const u16* __restrict__ Kg,
                                                 const u16* __restrict__ Vt,
                                                 u16* __restrict__ AO) {
  __shared__ __align__(16) u16 lK[2][128 * 64];  // [key][hd] XOR-swizzled, double-buffered
  __shared__ __align__(16) u16 lV[2][64 * 128];  // [hd][key] XOR-swizzled, double-buffered
  __shared__ __align__(16) u16 lP[4][16 * 128];  // per-wave P [q][key], swizzled

  const int tid = threadIdx.x;
  const int l = tid & 63, w = tid >> 6;
  const int lr = l >> 4, lc = l & 15;
  // id%8 == bh%8 (stable XCD per head-set) AND qt paired {gg, 31-gg} for balance
  const int id = blockIdx.x;
  const int bh = id & 31;
  const int s5 = (id >> 5) & 1;
  const int gg = id >> 6;
  const int qt = s5 ? (31 - gg) : gg;
  const int b = bh >> 4, h = bh & 15;

  const float slope = exp2f(-0.5f * (float)(h + 1));
  const int q_glob = qt * 64 + w * 16 + lc;

  bf16x8 qf[2];
#pragma unroll
  for (int ks = 0; ks < 2; ks++)
    qf[ks] = *(const bf16x8*)(Q + (size_t)(b * SS + q_glob) * DDIM + h * HDIM + ks * 32 + lr * 8);

  f32x4 of[4];
#pragma unroll
  for (int mf = 0; mf < 4; mf++) of[mf] = f32x4{0.f, 0.f, 0.f, 0.f};
  float mrun = -INFINITY, lrun = 0.f;

  const int srowK = l >> 3;
  const int scolK = ((l & 7) ^ srowK) * 8;
  const int nkt = qt / 2 + 1;
  char* lPw = (char*)lP[w];

  auto stage = [&](int kt, int bb) {
#pragma unroll
    for (int i = 0; i < 4; i++) {
      int c = w * 4 + i;
      gload16(Kg + (size_t)(b * SS + kt * 128 + c * 8 + srowK) * DDIM + h * HDIM + scolK,
              (char*)lK[bb] + c * 1024);
      int hd = c * 4 + lr;
      gload16(Vt + ((size_t)bh * HDIM + hd) * SS + kt * 128 + (((l & 15) ^ (hd & 7)) << 3),
              (char*)lV[bb] + c * 1024);
    }
  };

  // prologue: stage tile 0, drain, barrier
  stage(0, 0);
  asm volatile("s_waitcnt vmcnt(0)" ::: "memory");
  __builtin_amdgcn_s_barrier();
  asm volatile("" ::: "memory");

  // 2-phase pipeline: issue stage(kt+1) -> compute(kt) -> vmcnt(0)+barrier
  for (int kt = 0; kt < nkt - 1; kt++) {
    const int cur = kt & 1;
    stage(kt + 1, cur ^ 1);
    attn_tile(kt, false, 8, (const char*)lK[cur], (const char*)lV[cur], lPw,
              qf, of, mrun, lrun, slope, lr, lc, q_glob);
    asm volatile("s_waitcnt vmcnt(0)" ::: "memory");
    __builtin_amdgcn_s_barrier();
    asm volatile("" ::: "memory");
  }
  const int cur = (nkt - 1) & 1;
  if (qt & 1)
    attn_tile(nkt - 1, true, 8, (const char*)lK[cur], (const char*)lV[cur], lPw,
              qf, of, mrun, lrun, slope, lr, lc, q_glob);
  else
    attn_tile(nkt - 1, true, 4, (const char*)lK[cur], (const char*)lV[cur], lPw,
              qf, of, mrun, lrun, slope, lr, lc, q_glob);

  float inv = 1.f / lrun;
  u16* obase = AO + (size_t)(b * SS + q_glob) * DDIM + h * HDIM;
#pragma unroll
  for (int mf = 0; mf < 4; mf++) {
    uint2 uu;
    uu.x = f2bf(of[mf][0] * inv) | (f2bf(of[mf][1] * inv) << 16);
    uu.y = f2bf(of[mf][2] * inv) | (f2bf(of[mf][3] * inv) << 16);
    *(uint2*)(obase + mf * 16 + lr * 4) = uu;
  }
}

extern "C" void kernel_launch(void* const* d_in, const int* in_sizes, int n_in,
                              void* d_out, int out_size, void* d_ws, size_t ws_size,
                              hipStream_t stream) {
  const float* x  = (const float*)d_in[0];
  const float* Wq = (const float*)d_in[1];
  const float* bq = (const float*)d_in[2];
  const float* Wk = (const float*)d_in[3];
  const float* Wv = (const float*)d_in[4];
  const float* Wo = (const float*)d_in[5];
  const float* bo = (const float*)d_in[6];
  float* out = (float*)d_out;

  u16* ws = (u16*)d_ws;
  const size_t MEG = 1024 * 1024;
  u16* xb = ws;                  // 4M elems
  u16* WT = ws + 4 * MEG;        // 4 x 1M elems: WqT,WkT,WvT,WoT
  u16* Qb = ws + 8 * MEG;        // 4M
  u16* Kb = ws + 12 * MEG;       // 4M
  u16* Vt = ws + 16 * MEG;       // 4M  [32][64][2048]
  u16* AO = ws + 20 * MEG;       // 4M

  k_convert_x<<<dim3(4096), dim3(256), 0, stream>>>(x, xb);
  k_transpose_w<<<dim3(16, 16, 4), dim3(256), 0, stream>>>(Wq, Wk, Wv, Wo, WT);
  k_gemm<0><<<dim3(32, 24), dim3(256), 0, stream>>>(xb, WT, bq, (void*)Qb, (void*)Kb, (void*)Vt);
  k_attn<<<dim3(1024), dim3(256), 0, stream>>>(Qb, Kb, Vt, AO);
  k_gemm<1><<<dim3(32, 8), dim3(256), 0, stream>>>(AO, WT + 3 * MEG, bo, (void*)out, nullptr, nullptr);
}